// Round 3
// baseline (551.074 us; speedup 1.0000x reference)
//
#include <hip/hip_runtime.h>
#include <hip/hip_fp16.h>
#include <math.h>

// GraphSAGE mean, 2 layers. F_IN=5, F_HID=5, F_OUT=10.
// R19: SORT-FREE aggregation. R18 post-mortem showed sortagg1's 42.4us is
// invariant to gather/writeback micro-opts -> the counting-sort machinery
// (rank atomics + scan + scattered place + 25.6MB writeback + layer2 re-read)
// IS the cost. The sorted list's only consumer was layer2's k-ranges, so:
//  - agg1: per bucket, stream unsorted entries, gather xh[src],
//          LDS float atomicAdd into acc[2][128][5] (+deg atomic). -> hp, rdeg.
//  - agg2: same over hp with rdeg. -> out.
// DS-atomic budget: 6.4M edges x ~6 lane-atomics / 64 = ~600k wave-atomics
// x ~6cyc = ~6us of DS pipe device-wide, replacing ~40us of sort+writeback.
// R17 lesson kept: no grid-wide fusion (cg sync ~150us each on this runtime).

#define F_IN  5
#define F_HID 5
#define F_OUT 10

#define NBSHIFT 7                 // nodes per bucket = 128
#define NPB     (1 << NBSHIFT)    // 128
#define PBLK    1024              // partition block size
#define CHUNK   8192              // edges per partition block
#define EPT     8                 // edges per thread in partition
#define BSTRIDE 9216              // bucket stride: mean 8184 + ~11 sigma
#define ABLK    256               // agg block size (4 blocks/CU, all resident)
#define REP     2                 // LDS accumulator replicas (halve RMW chains)

__device__ __forceinline__ float sigmoidf(float v) {
    return 1.0f / (1.0f + __expf(-v));
}

__device__ __forceinline__ uint4 pack_h5(const float* __restrict__ xr) {
    float4 a = *(const float4*)xr;
    float a4 = xr[4];
    uint4 o;
    o.x = (unsigned)__half_as_ushort(__float2half_rn(a.x)) |
          ((unsigned)__half_as_ushort(__float2half_rn(a.y)) << 16);
    o.y = (unsigned)__half_as_ushort(__float2half_rn(a.z)) |
          ((unsigned)__half_as_ushort(__float2half_rn(a.w)) << 16);
    o.z = (unsigned)__half_as_ushort(__float2half_rn(a4));
    o.w = 0;
    return o;
}

// unpack 5 halves from a uint4 row
__device__ __forceinline__ void unp5(uint4 q, float* f) {
    float2 f01 = __half22float2(*(const __half2*)&q.x);
    float2 f23 = __half22float2(*(const __half2*)&q.y);
    float2 f45 = __half22float2(*(const __half2*)&q.z);
    f[0] = f01.x; f[1] = f01.y; f[2] = f23.x; f[3] = f23.y; f[4] = f45.x;
}

// ---- K1: partition edges by dst>>7 (cursor-first, 1 LDS atomic/edge);
//      each block also converts its 128-node slice of x to fp16 uint4 rows ----
__global__ void partition(const float* __restrict__ x,
                          const int* __restrict__ src, const int* __restrict__ dst,
                          int* __restrict__ bcursor, int* __restrict__ packed,
                          uint4* __restrict__ xh, int E, int N, int NB) {
    __shared__ int cnt[PBLK], excl[PBLK], adj[PBLK];
    __shared__ int wsum[16];
    __shared__ int buf[CHUNK];
    __shared__ unsigned char dlow[CHUNK];
    int t = threadIdx.x;
    int lane = t & 63, w = t >> 6;
    if (t < NPB) {
        int v = (blockIdx.x << NBSHIFT) + t;
        if (v < N) xh[v] = pack_h5(x + (size_t)v * 5);
    }
    cnt[t] = 0;
    __syncthreads();
    int base = blockIdx.x * CHUNK;
    int end  = min(base + CHUNK, E);
    // phase 0: vector-stage src/dst
    int sarr[EPT], darr[EPT];
    #pragma unroll
    for (int r = 0; r < 2; ++r) {
        int i = base + r * 4096 + t * 4;
        if (i + 4 <= end) {
            int4 sv = *(const int4*)(src + i);
            int4 dv = *(const int4*)(dst + i);
            sarr[r*4+0]=sv.x; sarr[r*4+1]=sv.y; sarr[r*4+2]=sv.z; sarr[r*4+3]=sv.w;
            darr[r*4+0]=dv.x; darr[r*4+1]=dv.y; darr[r*4+2]=dv.z; darr[r*4+3]=dv.w;
        } else {
            #pragma unroll
            for (int c = 0; c < 4; ++c) {
                int i2 = i + c;
                if (i2 < end) { sarr[r*4+c] = src[i2]; darr[r*4+c] = dst[i2]; }
            }
        }
    }
    // phase 1: rank via single LDS cursor atomic
    int esd[EPT];   // src | dlow<<17
    int ebp[EPT];   // b<<14 | p
    #pragma unroll
    for (int j = 0; j < EPT; ++j) {
        int i = base + (j >> 2) * 4096 + t * 4 + (j & 3);
        if (i < end) {
            int sv = sarr[j], d = darr[j];
            int b  = d >> NBSHIFT;
            int p  = atomicAdd(&cnt[b], 1);
            esd[j] = sv | ((d & (NPB - 1)) << 17);
            ebp[j] = (b << 14) | p;
        }
    }
    __syncthreads();
    // wave-shuffle inclusive scan of cnt[0..PBLK)
    int v = cnt[t];
    int incl = v;
    #pragma unroll
    for (int off = 1; off < 64; off <<= 1) {
        int u = __shfl_up(incl, off, 64);
        if (lane >= off) incl += u;
    }
    if (lane == 63) wsum[w] = incl;
    __syncthreads();
    if (t < 16) {
        int s = wsum[t];
        #pragma unroll
        for (int off = 1; off < 16; off <<= 1) {
            int u = __shfl_up(s, off, 16);
            if (t >= off) s += u;
        }
        wsum[t] = s;
    }
    __syncthreads();
    int wbase = (w > 0) ? wsum[w - 1] : 0;
    excl[t] = incl - v + wbase;
    __syncthreads();
    // reserve global space per bucket
    if (t < NB) {
        int cb = cnt[t];
        int go = cb ? atomicAdd(&bcursor[t], cb) : 0;
        adj[t] = t * BSTRIDE + go - excl[t];
    }
    __syncthreads();
    // phase 2: place from registers into LDS, bucket-grouped
    #pragma unroll
    for (int j = 0; j < EPT; ++j) {
        int i = base + (j >> 2) * 4096 + t * 4 + (j & 3);
        if (i < end) {
            int b   = ebp[j] >> 14;
            int pos = excl[b] + (ebp[j] & 0x3FFF);
            buf[pos]  = (esd[j] & 0x1FFFF) | (b << 17);
            dlow[pos] = (unsigned char)(esd[j] >> 17);
        }
    }
    __syncthreads();
    // phase 3: write runs out (consecutive pos -> same bucket -> coalesced)
    int cval = end - base;
    for (int p = t; p < cval; p += PBLK) {
        int e = buf[p];
        int b = e >> 17;
        packed[adj[b] + p] = (e & 0x1FFFF) | ((int)dlow[p] << 17);
    }
}

// ---- K2: layer-1 sort-free aggregation: LDS float atomics per bucket ----
__global__ void __launch_bounds__(ABLK, 4)
agg1(const uint4* __restrict__ xh, const int* __restrict__ packed,
     const int* __restrict__ bcursor,
     const float* __restrict__ Ws, const float* __restrict__ Wn,
     const float* __restrict__ bias,
     uint4* __restrict__ hp, float* __restrict__ rdeg, int N) {
    __shared__ float accf[REP * NPB * F_IN];
    __shared__ int ncnt[NPB];
    int b = blockIdx.x, t = threadIdx.x;
    int s0  = b * BSTRIDE;
    int cnt = min(bcursor[b], BSTRIDE);
    for (int i = t; i < REP * NPB * F_IN; i += ABLK) accf[i] = 0.0f;
    if (t < NPB) ncnt[t] = 0;
    __syncthreads();
    int rep = t & (REP - 1);
    for (int i = t * 4; i < cnt; i += ABLK * 4) {
        if (i + 4 <= cnt) {
            int4 q = *(const int4*)(packed + s0 + i);
            int e0 = q.x, e1 = q.y, e2 = q.z, e3 = q.w;
            uint4 g0 = xh[e0 & 0x1FFFF];
            uint4 g1 = xh[e1 & 0x1FFFF];
            uint4 g2 = xh[e2 & 0x1FFFF];
            uint4 g3 = xh[e3 & 0x1FFFF];
            int n0 = (e0 >> 17) & (NPB - 1);
            int n1 = (e1 >> 17) & (NPB - 1);
            int n2 = (e2 >> 17) & (NPB - 1);
            int n3 = (e3 >> 17) & (NPB - 1);
            float f[F_IN];
            float* a;
            unp5(g0, f); a = accf + (rep * NPB + n0) * F_IN;
            atomicAdd(a+0,f[0]); atomicAdd(a+1,f[1]); atomicAdd(a+2,f[2]);
            atomicAdd(a+3,f[3]); atomicAdd(a+4,f[4]); atomicAdd(&ncnt[n0],1);
            unp5(g1, f); a = accf + (rep * NPB + n1) * F_IN;
            atomicAdd(a+0,f[0]); atomicAdd(a+1,f[1]); atomicAdd(a+2,f[2]);
            atomicAdd(a+3,f[3]); atomicAdd(a+4,f[4]); atomicAdd(&ncnt[n1],1);
            unp5(g2, f); a = accf + (rep * NPB + n2) * F_IN;
            atomicAdd(a+0,f[0]); atomicAdd(a+1,f[1]); atomicAdd(a+2,f[2]);
            atomicAdd(a+3,f[3]); atomicAdd(a+4,f[4]); atomicAdd(&ncnt[n2],1);
            unp5(g3, f); a = accf + (rep * NPB + n3) * F_IN;
            atomicAdd(a+0,f[0]); atomicAdd(a+1,f[1]); atomicAdd(a+2,f[2]);
            atomicAdd(a+3,f[3]); atomicAdd(a+4,f[4]); atomicAdd(&ncnt[n3],1);
        } else {
            for (int c = 0; c < 4; ++c) {
                if (i + c < cnt) {
                    int e = packed[s0 + i + c];
                    int n = (e >> 17) & (NPB - 1);
                    float f[F_IN];
                    unp5(xh[e & 0x1FFFF], f);
                    float* a = accf + (rep * NPB + n) * F_IN;
                    atomicAdd(a+0,f[0]); atomicAdd(a+1,f[1]); atomicAdd(a+2,f[2]);
                    atomicAdd(a+3,f[3]); atomicAdd(a+4,f[4]); atomicAdd(&ncnt[n],1);
                }
            }
        }
    }
    __syncthreads();
    if (t < NPB) {
        int node = (b << NBSHIFT) + t;
        if (node < N) {
            int dg = ncnt[t];
            float rd = 1.0f / fmaxf((float)dg, 1.0f);
            float ni[F_IN];
            #pragma unroll
            for (int f = 0; f < F_IN; ++f)
                ni[f] = (accf[t * F_IN + f] + accf[(NPB + t) * F_IN + f]) * rd;
            float xi[F_IN];
            unp5(xh[node], xi);
            unsigned short hu[F_HID];
            #pragma unroll
            for (int j = 0; j < F_HID; ++j) {
                float acc = bias[j];
                #pragma unroll
                for (int f = 0; f < F_IN; ++f)
                    acc += xi[f] * Ws[f * F_HID + j] + ni[f] * Wn[f * F_HID + j];
                hu[j] = __half_as_ushort(__float2half_rn(sigmoidf(acc)));
            }
            uint4 o;
            o.x = (unsigned)hu[0] | ((unsigned)hu[1] << 16);
            o.y = (unsigned)hu[2] | ((unsigned)hu[3] << 16);
            o.z = (unsigned)hu[4];
            o.w = 0;
            hp[node] = o;
            rdeg[node] = rd;
        }
    }
}

// ---- K3: layer-2 sort-free aggregation, same structure over hp ----
__global__ void __launch_bounds__(ABLK, 4)
agg2(const uint4* __restrict__ hp, const int* __restrict__ packed,
     const int* __restrict__ bcursor, const float* __restrict__ rdeg,
     const float* __restrict__ Ws, const float* __restrict__ Wn,
     const float* __restrict__ bias,
     float* __restrict__ out, int N) {
    __shared__ float accf[REP * NPB * F_HID];
    int b = blockIdx.x, t = threadIdx.x;
    int s0  = b * BSTRIDE;
    int cnt = min(bcursor[b], BSTRIDE);
    for (int i = t; i < REP * NPB * F_HID; i += ABLK) accf[i] = 0.0f;
    __syncthreads();
    int rep = t & (REP - 1);
    for (int i = t * 4; i < cnt; i += ABLK * 4) {
        if (i + 4 <= cnt) {
            int4 q = *(const int4*)(packed + s0 + i);
            int e0 = q.x, e1 = q.y, e2 = q.z, e3 = q.w;
            uint4 g0 = hp[e0 & 0x1FFFF];
            uint4 g1 = hp[e1 & 0x1FFFF];
            uint4 g2 = hp[e2 & 0x1FFFF];
            uint4 g3 = hp[e3 & 0x1FFFF];
            int n0 = (e0 >> 17) & (NPB - 1);
            int n1 = (e1 >> 17) & (NPB - 1);
            int n2 = (e2 >> 17) & (NPB - 1);
            int n3 = (e3 >> 17) & (NPB - 1);
            float f[F_HID];
            float* a;
            unp5(g0, f); a = accf + (rep * NPB + n0) * F_HID;
            atomicAdd(a+0,f[0]); atomicAdd(a+1,f[1]); atomicAdd(a+2,f[2]);
            atomicAdd(a+3,f[3]); atomicAdd(a+4,f[4]);
            unp5(g1, f); a = accf + (rep * NPB + n1) * F_HID;
            atomicAdd(a+0,f[0]); atomicAdd(a+1,f[1]); atomicAdd(a+2,f[2]);
            atomicAdd(a+3,f[3]); atomicAdd(a+4,f[4]);
            unp5(g2, f); a = accf + (rep * NPB + n2) * F_HID;
            atomicAdd(a+0,f[0]); atomicAdd(a+1,f[1]); atomicAdd(a+2,f[2]);
            atomicAdd(a+3,f[3]); atomicAdd(a+4,f[4]);
            unp5(g3, f); a = accf + (rep * NPB + n3) * F_HID;
            atomicAdd(a+0,f[0]); atomicAdd(a+1,f[1]); atomicAdd(a+2,f[2]);
            atomicAdd(a+3,f[3]); atomicAdd(a+4,f[4]);
        } else {
            for (int c = 0; c < 4; ++c) {
                if (i + c < cnt) {
                    int e = packed[s0 + i + c];
                    int n = (e >> 17) & (NPB - 1);
                    float f[F_HID];
                    unp5(hp[e & 0x1FFFF], f);
                    float* a = accf + (rep * NPB + n) * F_HID;
                    atomicAdd(a+0,f[0]); atomicAdd(a+1,f[1]); atomicAdd(a+2,f[2]);
                    atomicAdd(a+3,f[3]); atomicAdd(a+4,f[4]);
                }
            }
        }
    }
    __syncthreads();
    if (t < NPB) {
        int node = (b << NBSHIFT) + t;
        if (node < N) {
            float rd = rdeg[node];
            float ni[F_HID];
            #pragma unroll
            for (int f = 0; f < F_HID; ++f)
                ni[f] = (accf[t * F_HID + f] + accf[(NPB + t) * F_HID + f]) * rd;
            float hi[F_HID];
            unp5(hp[node], hi);
            float o[F_OUT];
            #pragma unroll
            for (int j = 0; j < F_OUT; ++j) {
                float acc = bias[j];
                #pragma unroll
                for (int f = 0; f < F_HID; ++f)
                    acc += hi[f] * Ws[f * F_OUT + j] + ni[f] * Wn[f * F_OUT + j];
                o[j] = sigmoidf(acc);
            }
            float* op = out + (size_t)node * F_OUT;
            #pragma unroll
            for (int j = 0; j < F_OUT; j += 2)
                *(float2*)(op + j) = make_float2(o[j], o[j + 1]);
        }
    }
}

extern "C" void kernel_launch(void* const* d_in, const int* in_sizes, int n_in,
                              void* d_out, int out_size, void* d_ws, size_t ws_size,
                              hipStream_t stream) {
    const float* x   = (const float*)d_in[0];
    const int*   src = (const int*)d_in[1];
    const int*   dst = (const int*)d_in[2];
    const float* Ws1 = (const float*)d_in[3];
    const float* Wn1 = (const float*)d_in[4];
    const float* b1  = (const float*)d_in[5];
    const float* Ws2 = (const float*)d_in[6];
    const float* Wn2 = (const float*)d_in[7];
    const float* b2  = (const float*)d_in[8];
    float* out = (float*)d_out;

    const int N  = in_sizes[0] / F_IN;        // 100000
    const int E  = in_sizes[1];               // 6400000
    const int NB = (N + NPB - 1) >> NBSHIFT;  // 782

    // workspace (4B units):
    // bcursor[1024] | xh[4N] | rdeg[N] | packed[NB*BSTRIDE] | hp[4N]
    int*   bcursor = (int*)d_ws;
    uint4* xh      = (uint4*)(bcursor + 1024);
    float* rdeg    = (float*)(xh + N);
    int*   packed  = (int*)(rdeg + N);
    uint4* hp      = (uint4*)(packed + (size_t)NB * BSTRIDE);

    const int ablocks = (E + CHUNK - 1) / CHUNK;  // 782

    (void)hipMemsetAsync(bcursor, 0, 1024 * sizeof(int), stream);
    partition<<<ablocks, PBLK, 0, stream>>>(x, src, dst, bcursor, packed, xh, E, N, NB);
    agg1<<<NB, ABLK, 0, stream>>>(xh, packed, bcursor, Ws1, Wn1, b1, hp, rdeg, N);
    agg2<<<NB, ABLK, 0, stream>>>(hp, packed, bcursor, rdeg, Ws2, Wn2, b2, out, N);
}